// Round 3
// baseline (593.651 us; speedup 1.0000x reference)
//
#include <hip/hip_runtime.h>

// MeanShift++ on a dense 3D grid — distinct-bin (shrinking) formulation.
//
// Identity 1: reference pipeline == 5-tap triangular conv [1,2,3,2,1]^3 over
// per-bin sums S and counts C:  X_new = (w*S)[bin] / (w*C)[bin].
// Identity 2: X_new depends ONLY on bin(X). So per step we evaluate the conv
// once per OCCUPIED BIN (count shrinks every step as mean-shift contracts),
// scatter the merged mass (W*newpos, W) for the next step, and per-entry /
// per-point state is recovered with 1-tap lookups.
//
// Ping-pong grids A/B; R holds per-bin conv results (never cleared — only
// bins written this step are read); claim bitmasks dedup the next bin list.

constexpr float BW   = 0.1f;
constexpr float TOL2 = 1e-6f;            // (1e-3)^2
constexpr int DIM  = 112, OFF = 56;      // bins in [-56,55]; |x|<5.6 covered
constexpr int DIM2 = DIM * DIM;
constexpr int CELLS = DIM * DIM * DIM;   // 1,404,928
constexpr int CLW = (CELLS + 31) / 32;   // claim bitmask words

typedef float vf2 __attribute__((ext_vector_type(2)));

__device__ __forceinline__ int clampb(int v) { return v < 0 ? 0 : (v > DIM - 1 ? DIM - 1 : v); }
__device__ __forceinline__ int binf(float v) { return clampb((int)(v / BW) + OFF); }  // IEEE div + trunc == ref
__device__ __forceinline__ int flatb(int bx, int by, int bz) { return (bx * DIM + by) * DIM + bz; }

__device__ __forceinline__ void pk_add(float* p, float a, float b) {
#if defined(__has_builtin) && __has_builtin(__builtin_amdgcn_global_atomic_fadd_v2f32)
    vf2 v = {a, b};
    __builtin_amdgcn_global_atomic_fadd_v2f32((vf2*)p, v);
#else
    atomicAdd(p, a);
    atomicAdd(p + 1, b);
#endif
}

// 5x5x5 triangular conv at bin (bx,by,bz); returns (nx,ny,nz, W=center count)
__device__ __forceinline__ float4 conv5(const float4* __restrict__ g, int bx, int by, int bz) {
    const float t[5] = {1.f, 2.f, 3.f, 2.f, 1.f};
    float sx = 0.f, sy = 0.f, sz = 0.f, sc = 0.f, W = 0.f;
    if (bx >= 2 && bx <= DIM - 3 && by >= 2 && by <= DIM - 3 && bz >= 2 && bz <= DIM - 3) {
        #pragma unroll
        for (int dx = 0; dx < 5; ++dx) {
            float wx = t[dx];
            #pragma unroll
            for (int dy = 0; dy < 5; ++dy) {
                float wxy = wx * t[dy];
                const float4* row = g + flatb(bx + dx - 2, by + dy - 2, bz - 2);
                #pragma unroll
                for (int dz = 0; dz < 5; ++dz) {
                    float w = wxy * t[dz];
                    float4 e = row[dz];
                    sx = fmaf(w, e.x, sx);
                    sy = fmaf(w, e.y, sy);
                    sz = fmaf(w, e.z, sz);
                    sc = fmaf(w, e.w, sc);
                    if (dx == 2 && dy == 2 && dz == 2) W = e.w;
                }
            }
        }
    } else {
        for (int dx = -2; dx <= 2; ++dx) {
            int ix = bx + dx; if ((unsigned)ix >= (unsigned)DIM) continue;
            float wx = t[dx + 2];
            for (int dy = -2; dy <= 2; ++dy) {
                int iy = by + dy; if ((unsigned)iy >= (unsigned)DIM) continue;
                float wxy = wx * t[dy + 2];
                for (int dz = -2; dz <= 2; ++dz) {
                    int iz = bz + dz; if ((unsigned)iz >= (unsigned)DIM) continue;
                    float w = wxy * t[dz + 2];
                    float4 e = g[flatb(ix, iy, iz)];
                    sx = fmaf(w, e.x, sx);
                    sy = fmaf(w, e.y, sy);
                    sz = fmaf(w, e.z, sz);
                    sc = fmaf(w, e.w, sc);
                    if (dx == 0 && dy == 0 && dz == 0) W = e.w;
                }
            }
        }
    }
    return make_float4(sx / sc, sy / sc, sz / sc, W);
}

// ---- step 0: scatter raw points into A ----
__global__ void k_scatter_points(const float* __restrict__ X, float4* __restrict__ grid, int n) {
    int i = blockIdx.x * blockDim.x + threadIdx.x;
    if (i >= n) return;
    float x = X[3 * i + 0], y = X[3 * i + 1], z = X[3 * i + 2];
    float* cell = (float*)&grid[flatb(binf(x), binf(y), binf(z))];
    pk_add(cell + 0, x, y);
    pk_add(cell + 2, z, 1.0f);
}

// ---- build list_1 (occupied bins), IDX (bin -> entry index) ----
__global__ void k_compact(const float4* __restrict__ grid, int* __restrict__ ebin0,
                          int* __restrict__ IDX, int* __restrict__ cnt1) {
    int i = blockIdx.x * blockDim.x + threadIdx.x;
    bool occ = (i < CELLS) && (grid[i].w > 0.0f);
    unsigned long long mask = __ballot(occ);
    int lane = threadIdx.x & 63;
    int wid = threadIdx.x >> 6;
    __shared__ int wbase[4];
    if (lane == 0) wbase[wid] = __popcll(mask);
    __syncthreads();
    if (threadIdx.x == 0) {
        int t0 = wbase[0], t1 = wbase[1], t2 = wbase[2], t3 = wbase[3];
        int tot = t0 + t1 + t2 + t3;
        int b = tot ? atomicAdd(cnt1, tot) : 0;
        wbase[0] = b; wbase[1] = b + t0; wbase[2] = b + t0 + t1; wbase[3] = b + t0 + t1 + t2;
    }
    __syncthreads();
    if (occ) {
        int idx = wbase[wid] + __popcll(mask & ((1ull << lane) - 1));
        ebin0[idx] = i;
        IDX[i] = idx;
    }
}

// ---- per-step fused kernel: conv -> R, scatter -> tgt, claim-dedup next list ----
template <bool LAST>
__launch_bounds__(256)
__global__ void k_step(const float4* __restrict__ src, float4* __restrict__ R,
                       float4* __restrict__ tgt, unsigned* __restrict__ clT,
                       const int* __restrict__ list, const int* __restrict__ pK,
                       int* __restrict__ listOut, int* __restrict__ pKout) {
    int i = blockIdx.x * blockDim.x + threadIdx.x;
    if (i >= *pK) return;
    int b = list[i];
    int bx = b / DIM2, rem = b % DIM2;
    int by = rem / DIM, bz = rem % DIM;
    float4 np = conv5(src, bx, by, bz);   // (nx,ny,nz, W)
    R[b] = np;
    if (!LAST) {
        int bn = flatb(binf(np.x), binf(np.y), binf(np.z));
        float* cell = (float*)&tgt[bn];
        pk_add(cell + 0, np.w * np.x, np.w * np.y);
        pk_add(cell + 2, np.w * np.z, np.w);
        unsigned word = (unsigned)bn >> 5, bit = 1u << (bn & 31);
        unsigned old = atomicOr(&clT[word], bit);
        if (!(old & bit)) {
            int j = atomicAdd(pKout, 1);
            listOut[j] = bn;
        }
    }
}

// ---- after step 1: per-point convergence (slot 1), epos init, clear A ----
__global__ void k_upd1(const float* __restrict__ X, int n, const float4* __restrict__ R,
                       float4* __restrict__ epos, const int* __restrict__ ebin0,
                       const int* __restrict__ pM0, float4* __restrict__ A,
                       unsigned* __restrict__ slots) {
    int idx = blockIdx.x * blockDim.x + threadIdx.x;
    float d2 = 0.0f;
    if (idx < n) {
        float x = X[3 * idx + 0], y = X[3 * idx + 1], z = X[3 * idx + 2];
        float4 p = R[flatb(binf(x), binf(y), binf(z))];
        float ex = p.x - x, ey = p.y - y, ez = p.z - z;
        d2 = fmaf(ex, ex, fmaf(ey, ey, ez * ez));
    } else {
        int j = idx - n;
        if (j < *pM0) {
            int b = ebin0[j];
            epos[j] = R[b];
            A[b] = make_float4(0.f, 0.f, 0.f, 0.f);
        }
    }
    #pragma unroll
    for (int off = 32; off > 0; off >>= 1)
        d2 = fmaxf(d2, __shfl_down(d2, off, 64));
    if ((threadIdx.x & 63) == 0)
        atomicMax(&slots[1], __float_as_uint(d2));
}

// ---- steps >=2: per-entry 1-tap update (slot s) + targeted clear of src grid ----
__global__ void k_upds(int s, int n, const float4* __restrict__ R, float4* __restrict__ epos,
                       const int* __restrict__ pM0, unsigned* __restrict__ slots,
                       const int* __restrict__ list, const int* __restrict__ pK,
                       float4* __restrict__ Gsrc, unsigned* __restrict__ clSrc, int doClear) {
    int idx = blockIdx.x * blockDim.x + threadIdx.x;
    float d2 = 0.0f;
    if (idx < n) {
        if (idx < *pM0) {
            bool done = false;
            for (int t = 1; t < s; ++t)
                done |= (__uint_as_float(slots[t]) <= TOL2);
            float4 p = epos[idx];
            float nx = p.x, ny = p.y, nz = p.z;
            if (!done) {
                float4 r = R[flatb(binf(p.x), binf(p.y), binf(p.z))];
                nx = r.x; ny = r.y; nz = r.z;
            }
            epos[idx] = make_float4(nx, ny, nz, p.w);
            float ex = nx - p.x, ey = ny - p.y, ez = nz - p.z;
            d2 = fmaf(ex, ex, fmaf(ey, ey, ez * ez));
        }
    } else if (doClear) {
        int j = idx - n;
        if (j < *pK) {
            int b = list[j];
            Gsrc[b] = make_float4(0.f, 0.f, 0.f, 0.f);
            atomicAnd(&clSrc[(unsigned)b >> 5], ~(1u << (b & 31)));
        }
    }
    #pragma unroll
    for (int off = 32; off > 0; off >>= 1)
        d2 = fmaxf(d2, __shfl_down(d2, off, 64));
    if ((threadIdx.x & 63) == 0)
        atomicMax(&slots[s], __float_as_uint(d2));
}

// ---- final per-point output: freeze-aware lookup through entry state ----
__global__ void k_map(const float* __restrict__ X, int n, const int* __restrict__ IDX,
                      const float4* __restrict__ epos, const float4* __restrict__ R,
                      const unsigned* __restrict__ slots, float* __restrict__ out) {
    int i = blockIdx.x * blockDim.x + threadIdx.x;
    if (i >= n) return;
    bool done = false;
    for (int t = 1; t <= 4; ++t)
        done |= (__uint_as_float(slots[t]) <= TOL2);
    float x = X[3 * i + 0], y = X[3 * i + 1], z = X[3 * i + 2];
    int e = IDX[flatb(binf(x), binf(y), binf(z))];
    float4 p = epos[e];
    float ox = p.x, oy = p.y, oz = p.z;
    if (!done) {
        float4 r = R[flatb(binf(p.x), binf(p.y), binf(p.z))];
        ox = r.x; oy = r.y; oz = r.z;
    }
    out[3 * i + 0] = ox;
    out[3 * i + 1] = oy;
    out[3 * i + 2] = oz;
}

extern "C" void kernel_launch(void* const* d_in, const int* in_sizes, int n_in,
                              void* d_out, int out_size, void* d_ws, size_t ws_size,
                              hipStream_t stream) {
    const float* X = (const float*)d_in[0];
    int n = in_sizes[0] / 3;

    // ws layout (~78.2 MB):
    // [0,256)        meta: int cnt[8] @0, uint slots[8] @32
    // claimA, claimB (CLW*4 each)
    // A, B, R        (CELLS*16 each)
    // IDX            (CELLS*4)
    // L0 (=ebin0 / lists 1,3,5), L1 (lists 2,4)  (n*4 each)
    // epos           (n*16)
    char* ws = (char*)d_ws;
    int*      cnt   = (int*)ws;          // cnt[s] = |list_s|
    unsigned* slots = (unsigned*)(ws + 32);
    size_t clB4 = (size_t)CLW * 4;
    size_t grB  = (size_t)CELLS * 16;
    unsigned* clA = (unsigned*)(ws + 256);
    unsigned* clB = (unsigned*)(ws + 256 + clB4);
    float4* A   = (float4*)(ws + 256 + 2 * clB4);
    float4* B   = (float4*)((char*)A + grB);
    float4* R   = (float4*)((char*)B + grB);
    int*    IDX = (int*)((char*)R + grB);
    int*    L0  = (int*)((char*)IDX + (size_t)CELLS * 4);   // ebin0 / list 1,3,5
    int*    L1  = L0 + n;                                   // list 2,4
    float4* epos = (float4*)(L1 + n);

    // one memset: meta + claims + A + B  (R/IDX/lists/epos are write-before-read)
    hipMemsetAsync(ws, 0, 256 + 2 * clB4 + 2 * grB, stream);

    const int BLK = 256;
    int nbP = (n + BLK - 1) / BLK;
    int nbC = (CELLS + BLK - 1) / BLK;
    int nb2 = (2 * n + BLK - 1) / BLK;

    k_scatter_points<<<nbP, BLK, 0, stream>>>(X, A, n);
    k_compact<<<nbC, BLK, 0, stream>>>(A, L0, IDX, &cnt[1]);

    // step 1: src A -> tgt B, list L0, next list L1 (claims clB)
    k_step<false><<<nbP, BLK, 0, stream>>>(A, R, B, clB, L0, &cnt[1], L1, &cnt[2]);
    k_upd1<<<nb2, BLK, 0, stream>>>(X, n, R, epos, L0, &cnt[1], A, slots);

    // step 2: src B -> tgt A, list L1, next list L0 (claims clA); clear B+clB
    k_step<false><<<nbP, BLK, 0, stream>>>(B, R, A, clA, L1, &cnt[2], L0, &cnt[3]);
    k_upds<<<nb2, BLK, 0, stream>>>(2, n, R, epos, &cnt[1], slots, L1, &cnt[2], B, clB, 1);

    // step 3: src A -> tgt B, list L0, next list L1 (claims clB); clear A+clA
    k_step<false><<<nbP, BLK, 0, stream>>>(A, R, B, clB, L0, &cnt[3], L1, &cnt[4]);
    k_upds<<<nb2, BLK, 0, stream>>>(3, n, R, epos, &cnt[1], slots, L0, &cnt[3], A, clA, 1);

    // step 4: src B -> tgt A, list L1, next list L0 (claims clA); no clear needed
    k_step<false><<<nbP, BLK, 0, stream>>>(B, R, A, clA, L1, &cnt[4], L0, &cnt[5]);
    k_upds<<<nb2, BLK, 0, stream>>>(4, n, R, epos, &cnt[1], slots, L1, &cnt[4], B, clB, 0);

    // step 5: src A, conv only
    k_step<true><<<nbP, BLK, 0, stream>>>(A, R, nullptr, nullptr, L0, &cnt[5], nullptr, nullptr);

    k_map<<<nbP, BLK, 0, stream>>>(X, n, IDX, epos, R, slots, (float*)d_out);
}

// Round 4
// 345.250 us; speedup vs baseline: 1.7195x; 1.7195x over previous
//
#include <hip/hip_runtime.h>

// MeanShift++ on a dense 3D grid — distinct-bin (shrinking) formulation, v2.
// Round-4 changes vs round 3 (which regressed on same-address atomicMax):
//  - convergence = boolean OR flag per step (block-LDS reduce + plain store),
//    no per-wave atomicMax chains
//  - wave-aggregated list append in k_step (1 atomicAdd per wave, not per lane)
//  - grid-stride entry kernels; epos init fused into step-1 k_step
//  - final per-entry positions written to bin-keyed FIN grid -> k_map is 1 gather

constexpr float BW   = 0.1f;
constexpr float TOL2 = 1e-6f;            // (1e-3)^2
constexpr int DIM  = 112, OFF = 56;      // bins in [-56,55]; |x|<5.6 covered
constexpr int DIM2 = DIM * DIM;
constexpr int CELLS = DIM * DIM * DIM;   // 1,404,928 (divisible by 256)
constexpr int CLW = (CELLS + 31) / 32;

typedef float vf2 __attribute__((ext_vector_type(2)));

__device__ __forceinline__ int clampb(int v) { return v < 0 ? 0 : (v > DIM - 1 ? DIM - 1 : v); }
__device__ __forceinline__ int binf(float v) { return clampb((int)(v / BW) + OFF); }  // IEEE div+trunc == ref
__device__ __forceinline__ int flatb(int bx, int by, int bz) { return (bx * DIM + by) * DIM + bz; }

__device__ __forceinline__ void pk_add(float* p, float a, float b) {
#if defined(__has_builtin) && __has_builtin(__builtin_amdgcn_global_atomic_fadd_v2f32)
    vf2 v = {a, b};
    __builtin_amdgcn_global_atomic_fadd_v2f32((vf2*)p, v);
#else
    atomicAdd(p, a);
    atomicAdd(p + 1, b);
#endif
}

// 5x5x5 triangular conv [1,2,3,2,1]^3; returns (nx,ny,nz, W=center count)
__device__ __forceinline__ float4 conv5(const float4* __restrict__ g, int bx, int by, int bz) {
    const float t[5] = {1.f, 2.f, 3.f, 2.f, 1.f};
    float sx = 0.f, sy = 0.f, sz = 0.f, sc = 0.f, W = 0.f;
    if (bx >= 2 && bx <= DIM - 3 && by >= 2 && by <= DIM - 3 && bz >= 2 && bz <= DIM - 3) {
        #pragma unroll
        for (int dx = 0; dx < 5; ++dx) {
            float wx = t[dx];
            #pragma unroll
            for (int dy = 0; dy < 5; ++dy) {
                float wxy = wx * t[dy];
                const float4* row = g + flatb(bx + dx - 2, by + dy - 2, bz - 2);
                #pragma unroll
                for (int dz = 0; dz < 5; ++dz) {
                    float w = wxy * t[dz];
                    float4 e = row[dz];
                    sx = fmaf(w, e.x, sx);
                    sy = fmaf(w, e.y, sy);
                    sz = fmaf(w, e.z, sz);
                    sc = fmaf(w, e.w, sc);
                    if (dx == 2 && dy == 2 && dz == 2) W = e.w;
                }
            }
        }
    } else {
        for (int dx = -2; dx <= 2; ++dx) {
            int ix = bx + dx; if ((unsigned)ix >= (unsigned)DIM) continue;
            float wx = t[dx + 2];
            for (int dy = -2; dy <= 2; ++dy) {
                int iy = by + dy; if ((unsigned)iy >= (unsigned)DIM) continue;
                float wxy = wx * t[dy + 2];
                for (int dz = -2; dz <= 2; ++dz) {
                    int iz = bz + dz; if ((unsigned)iz >= (unsigned)DIM) continue;
                    float w = wxy * t[dz + 2];
                    float4 e = g[flatb(ix, iy, iz)];
                    sx = fmaf(w, e.x, sx);
                    sy = fmaf(w, e.y, sy);
                    sz = fmaf(w, e.z, sz);
                    sc = fmaf(w, e.w, sc);
                    if (dx == 0 && dy == 0 && dz == 0) W = e.w;
                }
            }
        }
    }
    return make_float4(sx / sc, sy / sc, sz / sc, W);
}

__global__ void k_scatter_points(const float* __restrict__ X, float4* __restrict__ grid, int n) {
    int i = blockIdx.x * blockDim.x + threadIdx.x;
    if (i >= n) return;
    float x = X[3 * i + 0], y = X[3 * i + 1], z = X[3 * i + 2];
    float* cell = (float*)&grid[flatb(binf(x), binf(y), binf(z))];
    pk_add(cell + 0, x, y);
    pk_add(cell + 2, z, 1.0f);
}

// occupied bins of A -> E0 list (entry order); M0 -> cnt1
__global__ void k_compact(const float4* __restrict__ grid, int* __restrict__ E0,
                          int* __restrict__ cnt1) {
    int i = blockIdx.x * blockDim.x + threadIdx.x;
    bool occ = grid[i].w > 0.0f;
    unsigned long long mask = __ballot(occ);
    int lane = threadIdx.x & 63;
    int wid = threadIdx.x >> 6;
    __shared__ int wbase[4];
    if (lane == 0) wbase[wid] = __popcll(mask);
    __syncthreads();
    if (threadIdx.x == 0) {
        int t0 = wbase[0], t1 = wbase[1], t2 = wbase[2], t3 = wbase[3];
        int tot = t0 + t1 + t2 + t3;
        int b = tot ? atomicAdd(cnt1, tot) : 0;
        wbase[0] = b; wbase[1] = b + t0; wbase[2] = b + t0 + t1; wbase[3] = b + t0 + t1 + t2;
    }
    __syncthreads();
    if (occ) E0[wbase[wid] + __popcll(mask & ((1ull << lane) - 1))] = i;
}

// MODE 0: step 1 (also init epos[i]); MODE 1: mid steps; MODE 2: last (conv only)
template <int MODE>
__launch_bounds__(256)
__global__ void k_step(const float4* __restrict__ src, float4* __restrict__ R,
                       float4* __restrict__ epos, float4* __restrict__ tgt,
                       unsigned* __restrict__ clT, const int* __restrict__ list,
                       const int* __restrict__ pK, int* __restrict__ listOut,
                       int* __restrict__ pKout) {
    int K = *pK;
    int lane = threadIdx.x & 63;
    for (int i = blockIdx.x * blockDim.x + threadIdx.x; i < K; i += gridDim.x * blockDim.x) {
        int b = list[i];
        int bx = b / DIM2, rem = b % DIM2;
        int by = rem / DIM, bz = rem % DIM;
        float4 np = conv5(src, bx, by, bz);
        R[b] = np;
        if (MODE == 0) epos[i] = np;
        if (MODE != 2) {
            int bn = flatb(binf(np.x), binf(np.y), binf(np.z));
            float* cell = (float*)&tgt[bn];
            pk_add(cell + 0, np.w * np.x, np.w * np.y);
            pk_add(cell + 2, np.w * np.z, np.w);
            unsigned old = atomicOr(&clT[(unsigned)bn >> 5], 1u << (bn & 31));
            bool isNew = !(old & (1u << (bn & 31)));
            // wave-aggregated append: one atomicAdd per wave
            unsigned long long m = __ballot(isNew);
            if (m) {
                int leader = (int)__ffsll((long long)m) - 1;
                int base;
                if (lane == leader) base = atomicAdd(pKout, __popcll(m));
                base = __shfl(base, leader, 64);
                if (isNew) listOut[base + __popcll(m & ((1ull << lane) - 1))] = bn;
            }
        }
    }
}

// after step 1: per-point convergence flag (notConv[1]) + targeted clear of A
__launch_bounds__(256)
__global__ void k_upd1(const float* __restrict__ X, int n, const float4* __restrict__ R,
                       const int* __restrict__ E0, const int* __restrict__ pM0,
                       float4* __restrict__ A, unsigned* __restrict__ notConv) {
    __shared__ unsigned sFlag;
    if (threadIdx.x == 0) sFlag = 0;
    __syncthreads();
    int M0 = *pM0;
    bool moved = false;
    for (int idx = blockIdx.x * blockDim.x + threadIdx.x; idx < n + M0;
         idx += gridDim.x * blockDim.x) {
        if (idx < n) {
            float x = X[3 * idx + 0], y = X[3 * idx + 1], z = X[3 * idx + 2];
            float4 p = R[flatb(binf(x), binf(y), binf(z))];
            float ex = p.x - x, ey = p.y - y, ez = p.z - z;
            moved |= (fmaf(ex, ex, fmaf(ey, ey, ez * ez)) > TOL2);
        } else {
            A[E0[idx - n]] = make_float4(0.f, 0.f, 0.f, 0.f);
        }
    }
    if (moved) sFlag = 1;           // same-value LDS races are fine
    __syncthreads();
    if (threadIdx.x == 0 && sFlag) notConv[1] = 1u;  // plain store, no RMW
}

// steps >=2: per-entry update (flag notConv[s]) + targeted clear of old src grid+claims
__launch_bounds__(256)
__global__ void k_upds(int s, const float4* __restrict__ R, float4* __restrict__ epos,
                       const int* __restrict__ pM0, unsigned* __restrict__ notConv,
                       const int* __restrict__ clearList, const int* __restrict__ pKc,
                       float4* __restrict__ Gsrc, unsigned* __restrict__ clSrc, int doClear) {
    __shared__ unsigned sFlag;
    if (threadIdx.x == 0) sFlag = 0;
    __syncthreads();
    int M0 = *pM0;
    int Kc = doClear ? *pKc : 0;
    bool done = false;
    for (int t = 1; t < s; ++t) done |= (notConv[t] == 0u);
    bool moved = false;
    for (int idx = blockIdx.x * blockDim.x + threadIdx.x; idx < M0 + Kc;
         idx += gridDim.x * blockDim.x) {
        if (idx < M0) {
            float4 p = epos[idx];
            if (!done) {
                float4 r = R[flatb(binf(p.x), binf(p.y), binf(p.z))];
                float ex = r.x - p.x, ey = r.y - p.y, ez = r.z - p.z;
                moved |= (fmaf(ex, ex, fmaf(ey, ey, ez * ez)) > TOL2);
                epos[idx] = make_float4(r.x, r.y, r.z, p.w);
            }
        } else {
            int b = clearList[idx - M0];
            Gsrc[b] = make_float4(0.f, 0.f, 0.f, 0.f);
            atomicAnd(&clSrc[(unsigned)b >> 5], ~(1u << (b & 31)));
        }
    }
    if (moved) sFlag = 1;
    __syncthreads();
    if (threadIdx.x == 0 && sFlag) notConv[s] = 1u;
}

// final per-entry position -> FIN grid keyed by ORIGINAL bin
__launch_bounds__(256)
__global__ void k_upd_final(const float4* __restrict__ R, const float4* __restrict__ epos,
                            const int* __restrict__ pM0, const unsigned* __restrict__ notConv,
                            const int* __restrict__ E0, float4* __restrict__ FIN) {
    int M0 = *pM0;
    bool done = false;
    for (int t = 1; t <= 4; ++t) done |= (notConv[t] == 0u);
    for (int e = blockIdx.x * blockDim.x + threadIdx.x; e < M0;
         e += gridDim.x * blockDim.x) {
        float4 p = epos[e];
        if (!done) {
            float4 r = R[flatb(binf(p.x), binf(p.y), binf(p.z))];
            p.x = r.x; p.y = r.y; p.z = r.z;
        }
        FIN[E0[e]] = p;
    }
}

// per-point output: single gather through FIN
__global__ void k_map(const float* __restrict__ X, int n, const float4* __restrict__ FIN,
                      float* __restrict__ out) {
    int i = blockIdx.x * blockDim.x + threadIdx.x;
    if (i >= n) return;
    float x = X[3 * i + 0], y = X[3 * i + 1], z = X[3 * i + 2];
    float4 p = FIN[flatb(binf(x), binf(y), binf(z))];
    out[3 * i + 0] = p.x;
    out[3 * i + 1] = p.y;
    out[3 * i + 2] = p.z;
}

extern "C" void kernel_launch(void* const* d_in, const int* in_sizes, int n_in,
                              void* d_out, int out_size, void* d_ws, size_t ws_size,
                              hipStream_t stream) {
    const float* X = (const float*)d_in[0];
    int n = in_sizes[0] / 3;

    // ws layout (~70.3 MB):
    // [0,256): int cnt[8] @0, uint notConv[8] @32
    // clA, clB (CLW*4 each); A, B, R (CELLS*16 each); E0, LA, LB (n ints each);
    // epos (n float4)
    char* ws = (char*)d_ws;
    int*      cnt     = (int*)ws;
    unsigned* notConv = (unsigned*)(ws + 32);
    size_t clB4 = (size_t)CLW * 4;
    size_t grB  = (size_t)CELLS * 16;
    unsigned* clA = (unsigned*)(ws + 256);
    unsigned* clB = (unsigned*)(ws + 256 + clB4);
    float4* A   = (float4*)(ws + 256 + 2 * clB4);
    float4* B   = (float4*)((char*)A + grB);
    float4* R   = (float4*)((char*)B + grB);
    int*    E0  = (int*)((char*)R + grB);
    int*    LA  = E0 + n;
    int*    LB  = LA + n;
    float4* epos = (float4*)(LB + n);

    hipMemsetAsync(ws, 0, 256 + 2 * clB4 + 2 * grB, stream);  // meta+claims+A+B

    const int BLK = 256;
    int nbP = (n + BLK - 1) / BLK;
    int nbC = CELLS / BLK;

    k_scatter_points<<<nbP, BLK, 0, stream>>>(X, A, n);
    k_compact<<<nbC, BLK, 0, stream>>>(A, E0, &cnt[1]);

    // step 1: A -> B (claims clB), list E0, next list LA; epos init fused
    k_step<0><<<512, BLK, 0, stream>>>(A, R, epos, B, clB, E0, &cnt[1], LA, &cnt[2]);
    k_upd1<<<1024, BLK, 0, stream>>>(X, n, R, E0, &cnt[1], A, notConv);

    // step 2: B -> A (claims clA), list LA, next LB; then clear B+clB via LA
    k_step<1><<<512, BLK, 0, stream>>>(B, R, nullptr, A, clA, LA, &cnt[2], LB, &cnt[3]);
    k_upds<<<256, BLK, 0, stream>>>(2, R, epos, &cnt[1], notConv, LA, &cnt[2], B, clB, 1);

    // step 3: A -> B (claims clB), list LB, next LA; then clear A+clA via LB
    k_step<1><<<512, BLK, 0, stream>>>(A, R, nullptr, B, clB, LB, &cnt[3], LA, &cnt[4]);
    k_upds<<<256, BLK, 0, stream>>>(3, R, epos, &cnt[1], notConv, LB, &cnt[3], A, clA, 1);

    // step 4: B -> A (claims clA), list LA, next LB; no clear needed
    k_step<1><<<512, BLK, 0, stream>>>(B, R, nullptr, A, clA, LA, &cnt[4], LB, &cnt[5]);
    k_upds<<<256, BLK, 0, stream>>>(4, R, epos, &cnt[1], notConv, nullptr, nullptr,
                                    nullptr, nullptr, 0);

    // step 5: A, conv only
    k_step<2><<<512, BLK, 0, stream>>>(A, R, nullptr, nullptr, nullptr, LB, &cnt[5],
                                       nullptr, nullptr);

    // finalize: per-entry final pos -> FIN (reuse B), then 1-gather map
    k_upd_final<<<256, BLK, 0, stream>>>(R, epos, &cnt[1], notConv, E0, B);
    k_map<<<nbP, BLK, 0, stream>>>(X, n, B, (float*)d_out);
}

// Round 5
// 334.577 us; speedup vs baseline: 1.7743x; 1.0319x over previous
//
#include <hip/hip_runtime.h>

// MeanShift++ dense-grid, distinct-bin formulation, v3 (fused steps).
// Identity 1: ref pipeline == 5-tap triangular conv [1,2,3,2,1]^3 over per-bin
// sums/counts. Identity 2: result depends only on bin => per-step work is per
// OCCUPIED BIN (shrinking); per-point state recovered by 1-tap lookups.
// v3: R compressed to (IDX: bin->entry, RE: entry->float4) ping-pong; 3 scatter
// grids A/B/C so targeted clears are race-free inside fused kernels; upd(s)
// fused into step(s+1); B zeroed in scatter kernel, C in step-1 kernel.

constexpr float BW   = 0.1f;
constexpr float TOL2 = 1e-6f;            // (1e-3)^2
constexpr int DIM  = 112, OFF = 56;      // bins in [-56,55]; |x|<5.6 covered
constexpr int DIM2 = DIM * DIM;
constexpr int CELLS = DIM * DIM * DIM;   // 1,404,928 (divisible by 256)
constexpr int CLW = CELLS / 32;          // 43,904 mask words

typedef float vf2 __attribute__((ext_vector_type(2)));

__device__ __forceinline__ int clampb(int v) { return v < 0 ? 0 : (v > DIM - 1 ? DIM - 1 : v); }
__device__ __forceinline__ int binf(float v) { return clampb((int)(v / BW) + OFF); }  // IEEE div+trunc == ref
__device__ __forceinline__ int flatb(int bx, int by, int bz) { return (bx * DIM + by) * DIM + bz; }

__device__ __forceinline__ void pk_add(float* p, float a, float b) {
#if defined(__has_builtin) && __has_builtin(__builtin_amdgcn_global_atomic_fadd_v2f32)
    vf2 v = {a, b};
    __builtin_amdgcn_global_atomic_fadd_v2f32((vf2*)p, v);
#else
    atomicAdd(p, a);
    atomicAdd(p + 1, b);
#endif
}

// 5x5x5 triangular conv [1,2,3,2,1]^3; returns (nx,ny,nz, W=center count)
__device__ __forceinline__ float4 conv5(const float4* __restrict__ g, int bx, int by, int bz) {
    const float t[5] = {1.f, 2.f, 3.f, 2.f, 1.f};
    float sx = 0.f, sy = 0.f, sz = 0.f, sc = 0.f, W = 0.f;
    if (bx >= 2 && bx <= DIM - 3 && by >= 2 && by <= DIM - 3 && bz >= 2 && bz <= DIM - 3) {
        #pragma unroll
        for (int dx = 0; dx < 5; ++dx) {
            float wx = t[dx];
            #pragma unroll
            for (int dy = 0; dy < 5; ++dy) {
                float wxy = wx * t[dy];
                const float4* row = g + flatb(bx + dx - 2, by + dy - 2, bz - 2);
                #pragma unroll
                for (int dz = 0; dz < 5; ++dz) {
                    float w = wxy * t[dz];
                    float4 e = row[dz];
                    sx = fmaf(w, e.x, sx);
                    sy = fmaf(w, e.y, sy);
                    sz = fmaf(w, e.z, sz);
                    sc = fmaf(w, e.w, sc);
                    if (dx == 2 && dy == 2 && dz == 2) W = e.w;
                }
            }
        }
    } else {
        for (int dx = -2; dx <= 2; ++dx) {
            int ix = bx + dx; if ((unsigned)ix >= (unsigned)DIM) continue;
            float wx = t[dx + 2];
            for (int dy = -2; dy <= 2; ++dy) {
                int iy = by + dy; if ((unsigned)iy >= (unsigned)DIM) continue;
                float wxy = wx * t[dy + 2];
                for (int dz = -2; dz <= 2; ++dz) {
                    int iz = bz + dz; if ((unsigned)iz >= (unsigned)DIM) continue;
                    float w = wxy * t[dz + 2];
                    float4 e = g[flatb(ix, iy, iz)];
                    sx = fmaf(w, e.x, sx);
                    sy = fmaf(w, e.y, sy);
                    sz = fmaf(w, e.z, sz);
                    sc = fmaf(w, e.w, sc);
                    if (dx == 0 && dy == 0 && dz == 0) W = e.w;
                }
            }
        }
    }
    return make_float4(sx / sc, sy / sc, sz / sc, W);
}

// points -> A (atomics), plus streaming zero of grid B
__launch_bounds__(256)
__global__ void k_scatter(const float* __restrict__ X, int n, float4* __restrict__ A,
                          float4* __restrict__ zeroG) {
    int stride = gridDim.x * blockDim.x;
    int total = n + CELLS;
    for (int idx = blockIdx.x * blockDim.x + threadIdx.x; idx < total; idx += stride) {
        if (idx < n) {
            float x = X[3 * idx + 0], y = X[3 * idx + 1], z = X[3 * idx + 2];
            float* cell = (float*)&A[flatb(binf(x), binf(y), binf(z))];
            pk_add(cell + 0, x, y);
            pk_add(cell + 2, z, 1.0f);
        } else {
            zeroG[idx - n] = make_float4(0.f, 0.f, 0.f, 0.f);
        }
    }
}

// occupied bins of A -> E0 (entry order); M0 -> cnt1
__global__ void k_compact(const float4* __restrict__ grid, int* __restrict__ E0,
                          int* __restrict__ cnt1) {
    int i = blockIdx.x * blockDim.x + threadIdx.x;
    bool occ = grid[i].w > 0.0f;
    unsigned long long mask = __ballot(occ);
    int lane = threadIdx.x & 63;
    int wid = threadIdx.x >> 6;
    __shared__ int wbase[4];
    if (lane == 0) wbase[wid] = __popcll(mask);
    __syncthreads();
    if (threadIdx.x == 0) {
        int t0 = wbase[0], t1 = wbase[1], t2 = wbase[2], t3 = wbase[3];
        int tot = t0 + t1 + t2 + t3;
        int b = tot ? atomicAdd(cnt1, tot) : 0;
        wbase[0] = b; wbase[1] = b + t0; wbase[2] = b + t0 + t1; wbase[3] = b + t0 + t1 + t2;
    }
    __syncthreads();
    if (occ) E0[wbase[wid] + __popcll(mask & ((1ull << lane) - 1))] = i;
}

// Fused per-step kernel. Segmented grid-stride over:
//  [0,K)                conv items: conv5(src,list[i]) -> REo[i], IDXo[b]; optional
//                       eposInit[i]=np; optional scatter->tgt + claim clT + append listOut
//  [K,K+U)              upd items: X!=null -> per-point step-1 check (notConv flag only)
//                       else per-entry epos <- REp[IDXp[bin(epos)]] (freeze-aware)
//  [.., +CL)            targeted grid clear via clearList
//  [.., +zmW)           zero a claim mask
//  [.., +zgC)           streaming zero of a full grid
__launch_bounds__(256)
__global__ void k_fused(
    const float4* __restrict__ src, const int* __restrict__ list, const int* __restrict__ pK,
    float4* __restrict__ REo, int* __restrict__ IDXo, float4* __restrict__ eposInit,
    float4* __restrict__ tgt, unsigned* __restrict__ clT,
    int* __restrict__ listOut, int* __restrict__ pKout,
    int updS, const float* __restrict__ X, int n,
    const float4* __restrict__ REp, const int* __restrict__ IDXp,
    const int* __restrict__ pM0, float4* __restrict__ epos,
    unsigned* __restrict__ notConv,
    const int* __restrict__ clearList, const int* __restrict__ pKc,
    float4* __restrict__ clearGrid,
    unsigned* __restrict__ zeroMask, int zmW,
    float4* __restrict__ zeroGrid, int zgC) {
    __shared__ unsigned sFlag;
    if (threadIdx.x == 0) sFlag = 0;
    __syncthreads();
    int K = *pK;
    int U = (updS > 0) ? (X ? n : *pM0) : 0;
    int CL = clearList ? *pKc : 0;
    int total = K + U + CL + zmW + zgC;
    bool done = false;
    if (updS > 1) {
        for (int t = 1; t < updS; ++t) done |= (notConv[t] == 0u);
    }
    int lane = threadIdx.x & 63;
    bool moved = false;
    int stride = gridDim.x * blockDim.x;
    for (int idx = blockIdx.x * blockDim.x + threadIdx.x; idx < total; idx += stride) {
        if (idx < K) {
            int b = list[idx];
            int bx = b / DIM2, rem = b % DIM2;
            int by = rem / DIM, bz = rem % DIM;
            float4 np = conv5(src, bx, by, bz);
            REo[idx] = np;
            IDXo[b] = idx;
            if (eposInit) eposInit[idx] = np;
            if (tgt) {
                int bn = flatb(binf(np.x), binf(np.y), binf(np.z));
                float* cell = (float*)&tgt[bn];
                pk_add(cell + 0, np.w * np.x, np.w * np.y);
                pk_add(cell + 2, np.w * np.z, np.w);
                unsigned old = atomicOr(&clT[(unsigned)bn >> 5], 1u << (bn & 31));
                bool isNew = !(old & (1u << (bn & 31)));
                unsigned long long m = __ballot(isNew);
                if (m) {
                    int leader = (int)__ffsll((long long)m) - 1;
                    int base;
                    if (lane == leader) base = atomicAdd(pKout, __popcll(m));
                    base = __shfl(base, leader, 64);
                    if (isNew) listOut[base + __popcll(m & ((1ull << lane) - 1))] = bn;
                }
            }
        } else if (idx < K + U) {
            int e = idx - K;
            if (X) {  // per-point step-1 convergence check
                float x = X[3 * e + 0], y = X[3 * e + 1], z = X[3 * e + 2];
                int j = IDXp[flatb(binf(x), binf(y), binf(z))];
                float4 r = REp[j];
                float ex = r.x - x, ey = r.y - y, ez = r.z - z;
                moved |= (fmaf(ex, ex, fmaf(ey, ey, ez * ez)) > TOL2);
            } else if (!done) {  // per-entry update to step-(updS) position
                float4 p = epos[e];
                int j = IDXp[flatb(binf(p.x), binf(p.y), binf(p.z))];
                float4 r = REp[j];
                float ex = r.x - p.x, ey = r.y - p.y, ez = r.z - p.z;
                moved |= (fmaf(ex, ex, fmaf(ey, ey, ez * ez)) > TOL2);
                epos[e] = make_float4(r.x, r.y, r.z, p.w);
            }
        } else if (idx < K + U + CL) {
            clearGrid[clearList[idx - K - U]] = make_float4(0.f, 0.f, 0.f, 0.f);
        } else if (idx < K + U + CL + zmW) {
            zeroMask[idx - K - U - CL] = 0u;
        } else {
            zeroGrid[idx - K - U - CL - zmW] = make_float4(0.f, 0.f, 0.f, 0.f);
        }
    }
    if (moved) sFlag = 1;
    __syncthreads();
    if (threadIdx.x == 0 && updS > 0 && sFlag) notConv[updS] = 1u;
}

// final per-entry position (freeze-aware, step-5 conv via IDXa/REa) -> FIN[E0[e]]
__launch_bounds__(256)
__global__ void k_fin(const float4* __restrict__ REa, const int* __restrict__ IDXa,
                      const float4* __restrict__ epos, const int* __restrict__ E0,
                      const int* __restrict__ pM0, const unsigned* __restrict__ notConv,
                      float4* __restrict__ FIN) {
    int M0 = *pM0;
    bool done = false;
    for (int t = 1; t <= 4; ++t) done |= (notConv[t] == 0u);
    for (int e = blockIdx.x * blockDim.x + threadIdx.x; e < M0;
         e += gridDim.x * blockDim.x) {
        float4 p = epos[e];
        if (!done) {
            int j = IDXa[flatb(binf(p.x), binf(p.y), binf(p.z))];
            float4 r = REa[j];
            p.x = r.x; p.y = r.y; p.z = r.z;
        }
        FIN[E0[e]] = p;
    }
}

__global__ void k_map(const float* __restrict__ X, int n, const float4* __restrict__ FIN,
                      float* __restrict__ out) {
    int i = blockIdx.x * blockDim.x + threadIdx.x;
    if (i >= n) return;
    float x = X[3 * i + 0], y = X[3 * i + 1], z = X[3 * i + 2];
    float4 p = FIN[flatb(binf(x), binf(y), binf(z))];
    out[3 * i + 0] = p.x;
    out[3 * i + 1] = p.y;
    out[3 * i + 2] = p.z;
}

extern "C" void kernel_launch(void* const* d_in, const int* in_sizes, int n_in,
                              void* d_out, int out_size, void* d_ws, size_t ws_size,
                              hipStream_t stream) {
    const float* X = (const float*)d_in[0];
    int n = in_sizes[0] / 3;

    // ws layout (~92 MB):
    // meta(256) | m0,m1 (CLW*4 each) | A,B,C (CELLS*16 each) |
    // IDXa,IDXb (CELLS*4 each) | REa,REb,epos (n*16 each) | E0,La,Lb,Lc (n*4 each)
    char* ws = (char*)d_ws;
    int*      cnt     = (int*)ws;        // cnt[1..5] list sizes
    unsigned* notConv = (unsigned*)(ws + 32);
    size_t mB = (size_t)CLW * 4;
    size_t gB = (size_t)CELLS * 16;
    unsigned* m0 = (unsigned*)(ws + 256);
    unsigned* m1 = (unsigned*)(ws + 256 + mB);
    float4* A = (float4*)(ws + 256 + 2 * mB);
    float4* B = (float4*)((char*)A + gB);
    float4* C = (float4*)((char*)B + gB);
    int* IDXa = (int*)((char*)C + gB);
    int* IDXb = IDXa + CELLS;
    float4* REa  = (float4*)(IDXb + CELLS);
    float4* REb  = REa + n;
    float4* epos = REb + n;
    int* E0 = (int*)(epos + n);
    int* La = E0 + n;
    int* Lb = La + n;
    int* Lc = Lb + n;

    // zero: meta + masks + A only (B in k_scatter, C in F1; rest write-before-read)
    hipMemsetAsync(ws, 0, 256 + 2 * mB + gB, stream);

    const int BLK = 256;
    k_scatter<<<1024, BLK, 0, stream>>>(X, n, A, B);
    k_compact<<<CELLS / BLK, BLK, 0, stream>>>(A, E0, &cnt[1]);

    // F1 (step 1): conv A/E0 -> REa/IDXa, epos init; scatter->B (mask m0 -> La); zero C
    k_fused<<<1024, BLK, 0, stream>>>(A, E0, &cnt[1], REa, IDXa, epos,
                                      B, m0, La, &cnt[2],
                                      0, nullptr, n, nullptr, nullptr, nullptr, nullptr,
                                      notConv, nullptr, nullptr, nullptr,
                                      nullptr, 0, C, CELLS);
    // F2 (step 2): conv B/La -> REb/IDXb; scatter->C (m1 -> Lb); per-point upd1;
    //              clear A via E0; zero m0
    k_fused<<<1024, BLK, 0, stream>>>(B, La, &cnt[2], REb, IDXb, nullptr,
                                      C, m1, Lb, &cnt[3],
                                      1, X, n, REa, IDXa, &cnt[1], nullptr,
                                      notConv, E0, &cnt[1], A,
                                      m0, CLW, nullptr, 0);
    // F3 (step 3): conv C/Lb -> REa/IDXa; scatter->A (m0 -> Lc); upd2 (REb/IDXb);
    //              clear B via La; zero m1
    k_fused<<<1024, BLK, 0, stream>>>(C, Lb, &cnt[3], REa, IDXa, nullptr,
                                      A, m0, Lc, &cnt[4],
                                      2, nullptr, n, REb, IDXb, &cnt[1], epos,
                                      notConv, La, &cnt[2], B,
                                      m1, CLW, nullptr, 0);
    // F4 (step 4): conv A/Lc -> REb/IDXb; scatter->B (m1 -> La); upd3 (REa/IDXa)
    k_fused<<<1024, BLK, 0, stream>>>(A, Lc, &cnt[4], REb, IDXb, nullptr,
                                      B, m1, La, &cnt[5],
                                      3, nullptr, n, REa, IDXa, &cnt[1], epos,
                                      notConv, nullptr, nullptr, nullptr,
                                      nullptr, 0, nullptr, 0);
    // F5 (step 5): conv B/La -> REa/IDXa (conv only); upd4 (REb/IDXb)
    k_fused<<<1024, BLK, 0, stream>>>(B, La, &cnt[5], REa, IDXa, nullptr,
                                      nullptr, nullptr, nullptr, nullptr,
                                      4, nullptr, n, REb, IDXb, &cnt[1], epos,
                                      notConv, nullptr, nullptr, nullptr,
                                      nullptr, 0, nullptr, 0);

    // finalize into FIN=C (only E0 cells are later read), then per-point map
    k_fin<<<256, BLK, 0, stream>>>(REa, IDXa, epos, E0, &cnt[1], notConv, C);
    k_map<<<(n + BLK - 1) / BLK, BLK, 0, stream>>>(X, n, C, (float*)d_out);
}